// Round 8
// baseline (361.375 us; speedup 1.0000x reference)
//
#include <hip/hip_runtime.h>

#define B_ 32
#define N_ 4096
#define D_ 64
#define C_ 129
#define BC_ 4
#define CD_ (C_ * D_)     // 8256 floats per (tensor,b) center block
#define NCH_ 8            // chunks per (tensor,b) in streaming segsum
#define CHROWS_ (N_ / NCH_) // 512 rows per chunk
#define QROWS_ 8   // q-rows per attn block: 17 groups/b * 32 b = 544 blocks (2/CU co-resident)

// ---------------------------------------------------------------- counting sort
// Also zeroes the segsum last-block counters (pcnt) every iteration — ws is
// re-poisoned per iteration, and stream order guarantees this lands before
// k_segsum_stream starts (r3 lesson: all cross-launch state must be reset
// inside the captured graph).
__global__ __launch_bounds__(1024) void k_sort(const int* __restrict__ cl,
                                               float* __restrict__ counts,
                                               int* __restrict__ offsets,
                                               int* __restrict__ sidx,
                                               int* __restrict__ pcnt) {
    __shared__ int cnt[C_];
    __shared__ int base[C_];
    __shared__ int cur[C_];
    int bc = blockIdx.x, tid = threadIdx.x;
    if (bc == 0 && tid < 96) pcnt[tid] = 0;
    for (int i = tid; i < C_; i += 1024) { cnt[i] = 0; cur[i] = 0; }
    __syncthreads();
    const int4* g4 = (const int4*)(cl + bc * N_);
    for (int n = tid; n < N_ / 4; n += 1024) {
        int4 c4 = g4[n];
        atomicAdd(&cnt[c4.x], 1);
        atomicAdd(&cnt[c4.y], 1);
        atomicAdd(&cnt[c4.z], 1);
        atomicAdd(&cnt[c4.w], 1);
    }
    __syncthreads();
    if (tid < C_) {
        int acc = 0;
        for (int i = 0; i < tid; i++) acc += cnt[i];
        base[tid] = acc;
    }
    __syncthreads();
    for (int i = tid; i < C_; i += 1024) {
        counts[bc * C_ + i] = (float)cnt[i];
        offsets[bc * (C_ + 1) + i] = base[i];
    }
    if (tid == 0) offsets[bc * (C_ + 1) + C_] = N_;
    for (int n = tid; n < N_ / 4; n += 1024) {
        int4 c4 = g4[n];
        int n0 = n * 4;
        sidx[bc * N_ + base[c4.x] + atomicAdd(&cur[c4.x], 1)] = n0;
        sidx[bc * N_ + base[c4.y] + atomicAdd(&cur[c4.y], 1)] = n0 + 1;
        sidx[bc * N_ + base[c4.z] + atomicAdd(&cur[c4.z], 1)] = n0 + 2;
        sidx[bc * N_ + base[c4.w] + atomicAdd(&cur[c4.w], 1)] = n0 + 3;
    }
}

// ---------------------------------------------------------------- streaming segment sums
// r7 diagnostic: the gather segsum runs 41us COLD at 1.3 TB/s (latency-starved:
// sidx->addr dependency + ~2 iterations/wave). This version inverts it:
// COALESCED sequential reads of q/k/v (streaming, prefetch-friendly) with
// scatter-accumulate into per-cluster LDS accumulators (ds_add atomics).
// block = (tensor t, b, chunk of 512 rows): bid = chunk*96 + (t*32+b), so all
// 8 chunks of (t,b) AND the combiner sit on XCD b%8 (matches attn's swizzle).
// LDS 35KB -> 4 blocks/CU; unroll-8 -> 32KB loads in flight per block.
// Partials combined by the last-arriving block (threadfence + agent-scope
// counter; no block ever WAITS -> no deadlock mode).
__global__ __launch_bounds__(256) void k_segsum_stream(const float* __restrict__ q,
                                                       const float* __restrict__ k,
                                                       const float* __restrict__ v,
                                                       const int* __restrict__ cl,
                                                       const float* __restrict__ counts,
                                                       float* __restrict__ part,
                                                       int* __restrict__ pcnt,
                                                       float* __restrict__ sums) {
    __shared__ float acc[CD_];        // 33KB per-cluster accumulators
    __shared__ int cl_s[CHROWS_];     // 2KB cluster ids for this chunk
    __shared__ int lastflag;
    int bid = blockIdx.x;
    int tb = bid % 96;                // t*32 + b
    int chunk = bid / 96;
    int t = tb >> 5;
    int b = tb & 31;
    int bc = b & 3;
    int tid = threadIdx.x;
    const float* x = (t == 0) ? q : (t == 1) ? k : v;

    for (int i = tid; i < CD_; i += 256) acc[i] = 0.f;
    int n0 = chunk * CHROWS_;
    for (int i = tid; i < CHROWS_; i += 256) cl_s[i] = cl[bc * N_ + n0 + i];
    __syncthreads();

    const float4* x4 = (const float4*)(x + (size_t)b * N_ * D_) + (size_t)n0 * 16;
    int g = tid >> 4, d4 = tid & 15;  // 16 groups x 16 lanes; group g owns row r0+u*16+g
    for (int r0 = 0; r0 < CHROWS_; r0 += 128) {
        float4 xv0 = x4[(r0 + 0 * 16 + g) * 16 + d4];
        float4 xv1 = x4[(r0 + 1 * 16 + g) * 16 + d4];
        float4 xv2 = x4[(r0 + 2 * 16 + g) * 16 + d4];
        float4 xv3 = x4[(r0 + 3 * 16 + g) * 16 + d4];
        float4 xv4 = x4[(r0 + 4 * 16 + g) * 16 + d4];
        float4 xv5 = x4[(r0 + 5 * 16 + g) * 16 + d4];
        float4 xv6 = x4[(r0 + 6 * 16 + g) * 16 + d4];
        float4 xv7 = x4[(r0 + 7 * 16 + g) * 16 + d4];
        int c0 = cl_s[r0 + 0 * 16 + g], c1 = cl_s[r0 + 1 * 16 + g];
        int c2 = cl_s[r0 + 2 * 16 + g], c3 = cl_s[r0 + 3 * 16 + g];
        int c4_ = cl_s[r0 + 4 * 16 + g], c5 = cl_s[r0 + 5 * 16 + g];
        int c6 = cl_s[r0 + 6 * 16 + g], c7 = cl_s[r0 + 7 * 16 + g];
#define ACC1(cc, xv)                                            \
        {   float* pa = &acc[(cc) * 64 + d4 * 4];               \
            atomicAdd(pa + 0, (xv).x); atomicAdd(pa + 1, (xv).y); \
            atomicAdd(pa + 2, (xv).z); atomicAdd(pa + 3, (xv).w); }
        ACC1(c0, xv0) ACC1(c1, xv1) ACC1(c2, xv2) ACC1(c3, xv3)
        ACC1(c4_, xv4) ACC1(c5, xv5) ACC1(c6, xv6) ACC1(c7, xv7)
#undef ACC1
    }
    __syncthreads();

    // write partial (float4-coalesced)
    float4* my = (float4*)(part + ((size_t)tb * NCH_ + chunk) * CD_);
    const float4* accf4 = (const float4*)acc;
    for (int i = tid; i < CD_ / 4; i += 256) my[i] = accf4[i];

    __threadfence();   // make partial visible device-wide before signaling
    if (tid == 0) {
        int old = __hip_atomic_fetch_add(&pcnt[tb], 1, __ATOMIC_ACQ_REL,
                                         __HIP_MEMORY_SCOPE_AGENT);
        lastflag = (old == NCH_ - 1);
    }
    __syncthreads();
    if (lastflag) {
        __threadfence();   // acquire: invalidate caches before reading partials
        const float4* pt = (const float4*)(part + (size_t)tb * NCH_ * CD_);
        float4* dst = (float4*)(sums + (size_t)tb * CD_);   // tb == t*B_+b layout
        for (int i = tid; i < CD_ / 4; i += 256) {
            float4 s = accf4[i];   // own chunk straight from LDS
#pragma unroll
            for (int ch = 0; ch < NCH_; ch++) {
                if (ch == chunk) continue;
                float4 p = pt[ch * (CD_ / 4) + i];
                s.x += p.x; s.y += p.y; s.z += p.z; s.w += p.w;
            }
            int c = i >> 4;   // 16 float4 per cluster row
            float cnt = counts[bc * C_ + c];
            float w = (cnt > 0.f) ? 1.f / cnt : 0.f;
            s.x *= w; s.y *= w; s.z *= w; s.w *= w;
            dst[i] = s;
        }
    }
}

// ---------------------------------------------------------------- attention + scatter
// Unchanged from round 6 (best: 164.7 us). 544 blocks, 2/CU, XCD-local per b.
__global__ __launch_bounds__(256, 2) void k_attn_sc(const float* __restrict__ sums,
                                                    const float* __restrict__ counts,
                                                    const int* __restrict__ offsets,
                                                    const int* __restrict__ sidx,
                                                    float* __restrict__ out,
                                                    float* __restrict__ aout) {
    __shared__ float4 kc4[C_ * 17];       // K centers, 16 data float4 + 1 pad
    __shared__ float4 vc4[C_ * 17];       // V centers
    __shared__ float cnt_s[C_];
    __shared__ float arow[4][2][132];     // per-wave A rows (2-row tiles)

    int bid = blockIdx.x;
    int b = bid & 31;          // XCD-locality: blocks of batch b are == b (mod 32)
    int qg = bid >> 5;         // 0..16
    int q0 = qg * QROWS_;
    int qcnt = min(QROWS_, C_ - q0);
    int tid = threadIdx.x;
    int bc = b & 3;

    for (int i = tid; i < C_; i += 256)
        cnt_s[i] = counts[bc * C_ + i];

    const float4* qsum4 = (const float4*)(sums + (size_t)b * C_ * D_);
    const float4* ksum4 = (const float4*)(sums + ((size_t)B_ + b) * C_ * D_);
    const float4* vsum4 = (const float4*)(sums + ((size_t)2 * B_ + b) * C_ * D_);

    for (int i = tid; i < C_ * 16; i += 256) {
        int c = i >> 4, d4 = i & 15;
        kc4[c * 17 + d4] = ksum4[i];
        vc4[c * 17 + d4] = vsum4[i];
    }
    __syncthreads();

    const int* si = sidx + bc * N_;
    float4* ob = (float4*)(out + (size_t)b * N_ * D_);

    int wave = __builtin_amdgcn_readfirstlane(tid >> 6);
    int lane = tid & 63;

    for (int tt = wave; tt * 2 < qcnt; tt += 4) {
        int t2 = tt * 2;
        const float4* qp0 = qsum4 + (size_t)(q0 + min(t2 + 0, qcnt - 1)) * 16;
        const float4* qp1 = qsum4 + (size_t)(q0 + min(t2 + 1, qcnt - 1)) * 16;
        float s0[2] = {0, 0}, s1[2] = {0, 0}, s2[2] = {0, 0};
#pragma unroll 4
        for (int d4 = 0; d4 < 16; d4++) {
            float4 kv0 = kc4[lane * 17 + d4];
            float4 kv1 = kc4[(lane + 64) * 17 + d4];
            float4 kv2 = kc4[128 * 17 + d4];
            float4 qv0 = qp0[d4], qv1 = qp1[d4];
            s0[0] += qv0.x * kv0.x + qv0.y * kv0.y + qv0.z * kv0.z + qv0.w * kv0.w;
            s1[0] += qv0.x * kv1.x + qv0.y * kv1.y + qv0.z * kv1.z + qv0.w * kv1.w;
            s2[0] += qv0.x * kv2.x + qv0.y * kv2.y + qv0.z * kv2.z + qv0.w * kv2.w;
            s0[1] += qv1.x * kv0.x + qv1.y * kv0.y + qv1.z * kv0.z + qv1.w * kv0.w;
            s1[1] += qv1.x * kv1.x + qv1.y * kv1.y + qv1.z * kv1.z + qv1.w * kv1.w;
            s2[1] += qv1.x * kv2.x + qv1.y * kv2.y + qv1.z * kv2.z + qv1.w * kv2.w;
        }
#pragma unroll
        for (int r = 0; r < 2; r++) {
            if (t2 + r >= qcnt) break;
            int qrow = q0 + t2 + r;
            float m = fmaxf(s0[r], s1[r]);
            if (lane == 0) m = fmaxf(m, s2[r]);
            for (int off = 32; off > 0; off >>= 1)
                m = fmaxf(m, __shfl_xor(m, off, 64));
            float e0 = __expf(s0[r] - m) * cnt_s[lane];
            float e1 = __expf(s1[r] - m) * cnt_s[lane + 64];
            float e2 = (lane == 0) ? __expf(s2[r] - m) * cnt_s[128] : 0.f;
            float sum = e0 + e1 + e2;
            for (int off = 32; off > 0; off >>= 1)
                sum += __shfl_xor(sum, off, 64);
            float inv = 1.f / sum;
            float a0 = e0 * inv, a1 = e1 * inv;
            arow[wave][r][lane] = a0;
            arow[wave][r][64 + lane] = a1;
            if (lane == 0) {
                arow[wave][r][128] = e2 * inv;
                aout[b * C_ + qrow] = a0;   // A_full[:, :, 0]
            }
        }
        __builtin_amdgcn_s_waitcnt(0);       // arow writes visible in-wave
        __builtin_amdgcn_sched_barrier(0);   // don't let ds_reads hoist above
        int rr = lane >> 5;
        int half = (lane >> 4) & 1;
        int d4 = lane & 15;
        const float4* ar4 = (const float4*)arow[wave][rr];
        float4 o = make_float4(0.f, 0.f, 0.f, 0.f);
        int k4base = half * 16;
        for (int k4 = k4base; k4 < k4base + 16; k4++) {
            float4 a4 = ar4[k4];
            float4 v0 = vc4[(k4 * 4 + 0) * 17 + d4];
            float4 v1 = vc4[(k4 * 4 + 1) * 17 + d4];
            float4 v2 = vc4[(k4 * 4 + 2) * 17 + d4];
            float4 v3 = vc4[(k4 * 4 + 3) * 17 + d4];
            o.x += a4.x * v0.x + a4.y * v1.x + a4.z * v2.x + a4.w * v3.x;
            o.y += a4.x * v0.y + a4.y * v1.y + a4.z * v2.y + a4.w * v3.y;
            o.z += a4.x * v0.z + a4.y * v1.z + a4.z * v2.z + a4.w * v3.z;
            o.w += a4.x * v0.w + a4.y * v1.w + a4.z * v2.w + a4.w * v3.w;
        }
        o.x += __shfl_xor(o.x, 16, 64);
        o.y += __shfl_xor(o.y, 16, 64);
        o.z += __shfl_xor(o.z, 16, 64);
        o.w += __shfl_xor(o.w, 16, 64);
        {   // k=128 tail (identical in both halves; added AFTER the combine)
            float a128 = arow[wave][rr][128];
            float4 vv = vc4[128 * 17 + d4];
            o.x += a128 * vv.x; o.y += a128 * vv.y;
            o.z += a128 * vv.z; o.w += a128 * vv.w;
        }
        if (t2 + rr < qcnt) {
            int qrow = q0 + t2 + rr;
            int s = offsets[bc * (C_ + 1) + qrow];
            int e = offsets[bc * (C_ + 1) + qrow + 1];
            for (int mm = s + half; mm < e; mm += 2) {
                int n = si[mm];              // broadcast load (same addr, 16 lanes)
                ob[n * 16 + d4] = o;         // 16 lanes -> contiguous 256B row
            }
        }
    }
}

// ---------------------------------------------------------------- launch
extern "C" void kernel_launch(void* const* d_in, const int* in_sizes, int n_in,
                              void* d_out, int out_size, void* d_ws, size_t ws_size,
                              hipStream_t stream) {
    const float* q = (const float*)d_in[0];
    const float* k = (const float*)d_in[1];
    const float* v = (const float*)d_in[2];
    const int* cl = (const int*)d_in[3];
    float* out = (float*)d_out;
    float* aout = out + (size_t)B_ * N_ * D_;   // A_full[:, :, 0] tail

    float* ws = (float*)d_ws;
    float* counts = ws;                                   // [4][C_] (pad to 1024)
    float* sums = ws + 1024;                              // [3][B_][C_][D_] pre-scaled centers
    float* part = sums + (size_t)3 * B_ * CD_;            // [96][NCH_][C_*D_] partials
    int* pcnt = (int*)(part + (size_t)96 * NCH_ * CD_);   // [96] last-block counters (pad 256)
    int* offsets = pcnt + 256;                            // [4][C_+1]
    int* sidx = offsets + 4 * (C_ + 1);                   // [4][N_]

    k_sort<<<BC_, 1024, 0, stream>>>(cl, counts, offsets, sidx, pcnt);
    k_segsum_stream<<<NCH_ * 96, 256, 0, stream>>>(q, k, v, cl, counts, part, pcnt, sums);
    k_attn_sc<<<17 * B_, 256, 0, stream>>>(sums, counts, offsets, sidx, out, aout);
}

// Round 9
// 167.866 us; speedup vs baseline: 2.1528x; 2.1528x over previous
//
#include <hip/hip_runtime.h>

#define B_ 32
#define N_ 4096
#define D_ 64
#define C_ 129
#define BC_ 4
#define CG_ 33     // ceil(C_/4): 4 waves/block = 4 clusters/block
#define QROWS_ 8   // q-rows per attn block: 17 groups/b * 32 b = 544 blocks (2/CU co-resident)
#define PFB_ 252   // prefetch blocks appended to k_sort's grid

// ---------------------------------------------------------------- counting sort + L3 prefetch
// Blocks 0..3: counting sort (verified body). Blocks 4..255: stream-read all of
// q/k/v (96 MB < 256 MB Infinity Cache) so the NEXT kernel's latency-bound
// gathers hit L3 (~200-300cy) instead of cold HBM (~900cy). r7 measured:
// segsum cold=41us @1.3TB/s, L3-warm=~16us — the per-iteration 256MB ws
// re-poison evicts L3, so without this, segsum ALWAYS runs cold. Prefetch is
// streaming (latency-tolerant) and overlaps the sort, using CUs that idled.
__global__ __launch_bounds__(1024) void k_sort(const float* __restrict__ q,
                                               const float* __restrict__ k,
                                               const float* __restrict__ v,
                                               const int* __restrict__ cl,
                                               float* __restrict__ counts,
                                               int* __restrict__ offsets,
                                               int* __restrict__ sidx) {
    __shared__ int cnt[C_];
    __shared__ int base[C_];
    __shared__ int cur[C_];
    int bc = blockIdx.x, tid = threadIdx.x;

    if (bc >= BC_) {
        // ---- prefetch path: grid-stride float4 reads of q, k, v
        int pb = bc - BC_;
        const size_t total4 = (size_t)B_ * N_ * D_ / 4;   // 2,097,152 float4/tensor
        const float4* q4 = (const float4*)q;
        const float4* k4 = (const float4*)k;
        const float4* v4 = (const float4*)v;
        float4 s = make_float4(0.f, 0.f, 0.f, 0.f);
        for (size_t i = (size_t)pb * 1024 + tid; i < total4; i += (size_t)PFB_ * 1024) {
            float4 a = q4[i], b4 = k4[i], c4 = v4[i];
            s.x += a.x + b4.x + c4.x;
            s.y += a.y + b4.y + c4.y;
            s.z += a.z + b4.z + c4.z;
            s.w += a.w + b4.w + c4.w;
        }
        // keep the loads live without any store (guide rule #17: anti-DCE)
        asm volatile("" :: "v"(s.x), "v"(s.y), "v"(s.z), "v"(s.w));
        return;
    }

    // ---- sort path (verified, unchanged)
    for (int i = tid; i < C_; i += 1024) { cnt[i] = 0; cur[i] = 0; }
    __syncthreads();
    const int4* g4 = (const int4*)(cl + bc * N_);
    for (int n = tid; n < N_ / 4; n += 1024) {
        int4 c4 = g4[n];
        atomicAdd(&cnt[c4.x], 1);
        atomicAdd(&cnt[c4.y], 1);
        atomicAdd(&cnt[c4.z], 1);
        atomicAdd(&cnt[c4.w], 1);
    }
    __syncthreads();
    if (tid < C_) {
        int acc = 0;
        for (int i = 0; i < tid; i++) acc += cnt[i];
        base[tid] = acc;
    }
    __syncthreads();
    for (int i = tid; i < C_; i += 1024) {
        counts[bc * C_ + i] = (float)cnt[i];
        offsets[bc * (C_ + 1) + i] = base[i];
    }
    if (tid == 0) offsets[bc * (C_ + 1) + C_] = N_;
    for (int n = tid; n < N_ / 4; n += 1024) {
        int4 c4 = g4[n];
        int n0 = n * 4;
        sidx[bc * N_ + base[c4.x] + atomicAdd(&cur[c4.x], 1)] = n0;
        sidx[bc * N_ + base[c4.y] + atomicAdd(&cur[c4.y], 1)] = n0 + 1;
        sidx[bc * N_ + base[c4.z] + atomicAdd(&cur[c4.z], 1)] = n0 + 2;
        sidx[bc * N_ + base[c4.w] + atomicAdd(&cur[c4.w], 1)] = n0 + 3;
    }
}

// ---------------------------------------------------------------- fused segment sums
// r6-verified gather body, unchanged. One wave per (b, cluster); 12 independent
// row-gathers in flight; index prefetch pipelined. With the k_sort prefetch,
// these gathers are L3-hits (r8 post-mortem: the LDS-atomic streaming
// alternative was 6x SLOWER — scatter-accumulate via ds_add serializes).
__global__ __launch_bounds__(256) void k_segsum4(const float* __restrict__ q,
                                                 const float* __restrict__ k,
                                                 const float* __restrict__ v,
                                                 const int* __restrict__ offsets,
                                                 const int* __restrict__ sidx,
                                                 float* __restrict__ sums) {
    int bid = blockIdx.x;
    int cg = bid % CG_;
    int b = bid / CG_;
    int wave = threadIdx.x >> 6, lane = threadIdx.x & 63;
    int c = cg * 4 + wave;
    if (c >= C_) return;
    int bc = b & 3;
    int start = offsets[bc * (C_ + 1) + c];
    int end = offsets[bc * (C_ + 1) + c + 1];
    int cnt = end - start;
    int sub = lane >> 4, d4 = lane & 15;

    const float4* q4 = (const float4*)(q + (size_t)b * N_ * D_);
    const float4* k4 = (const float4*)(k + (size_t)b * N_ * D_);
    const float4* v4 = (const float4*)(v + (size_t)b * N_ * D_);
    const int* si = sidx + bc * N_;

    float4 aq = make_float4(0.f, 0.f, 0.f, 0.f);
    float4 ak = make_float4(0.f, 0.f, 0.f, 0.f);
    float4 av = make_float4(0.f, 0.f, 0.f, 0.f);

    if (cnt > 0) {
        int last = end - 1;
        int ia = start + sub, ib = ia + 4, ic = ia + 8, id = ia + 12;
        int ra = si[min(ia, last)], rb = si[min(ib, last)];
        int rc = si[min(ic, last)], rd = si[min(id, last)];
        for (int i0 = start; i0 < end; i0 += 16) {
            int ca = ia, cb = ib, cc = ic, cd = id;
            int ua = ra, ub = rb, uc = rc, ud = rd;
            ia += 16; ib += 16; ic += 16; id += 16;
            if (i0 + 16 < end) {
                ra = si[min(ia, last)]; rb = si[min(ib, last)];
                rc = si[min(ic, last)]; rd = si[min(id, last)];
            }
            float ma = (ca < end) ? 1.f : 0.f;
            float mb = (cb < end) ? 1.f : 0.f;
            float mc = (cc < end) ? 1.f : 0.f;
            float md = (cd < end) ? 1.f : 0.f;
            float4 qa = q4[ua * 16 + d4], qb = q4[ub * 16 + d4];
            float4 qc = q4[uc * 16 + d4], qd = q4[ud * 16 + d4];
            float4 ka = k4[ua * 16 + d4], kb = k4[ub * 16 + d4];
            float4 kc = k4[uc * 16 + d4], kd = k4[ud * 16 + d4];
            float4 va = v4[ua * 16 + d4], vb = v4[ub * 16 + d4];
            float4 vc = v4[uc * 16 + d4], vd = v4[ud * 16 + d4];
            aq.x += ma * qa.x + mb * qb.x + mc * qc.x + md * qd.x;
            aq.y += ma * qa.y + mb * qb.y + mc * qc.y + md * qd.y;
            aq.z += ma * qa.z + mb * qb.z + mc * qc.z + md * qd.z;
            aq.w += ma * qa.w + mb * qb.w + mc * qc.w + md * qd.w;
            ak.x += ma * ka.x + mb * kb.x + mc * kc.x + md * kd.x;
            ak.y += ma * ka.y + mb * kb.y + mc * kc.y + md * kd.y;
            ak.z += ma * ka.z + mb * kb.z + mc * kc.z + md * kd.z;
            ak.w += ma * ka.w + mb * kb.w + mc * kc.w + md * kd.w;
            av.x += ma * va.x + mb * vb.x + mc * vc.x + md * vd.x;
            av.y += ma * va.y + mb * vb.y + mc * vc.y + md * vd.y;
            av.z += ma * va.z + mb * vb.z + mc * vc.z + md * vd.z;
            av.w += ma * va.w + mb * vb.w + mc * vc.w + md * vd.w;
        }
    }
#pragma unroll
    for (int off = 16; off <= 32; off <<= 1) {
        aq.x += __shfl_xor(aq.x, off, 64); aq.y += __shfl_xor(aq.y, off, 64);
        aq.z += __shfl_xor(aq.z, off, 64); aq.w += __shfl_xor(aq.w, off, 64);
        ak.x += __shfl_xor(ak.x, off, 64); ak.y += __shfl_xor(ak.y, off, 64);
        ak.z += __shfl_xor(ak.z, off, 64); ak.w += __shfl_xor(ak.w, off, 64);
        av.x += __shfl_xor(av.x, off, 64); av.y += __shfl_xor(av.y, off, 64);
        av.z += __shfl_xor(av.z, off, 64); av.w += __shfl_xor(av.w, off, 64);
    }
    if (sub == 0) {
        float w = (cnt > 0) ? 1.f / (float)cnt : 0.f;
        float4 oq = make_float4(aq.x * w, aq.y * w, aq.z * w, aq.w * w);
        float4 ok = make_float4(ak.x * w, ak.y * w, ak.z * w, ak.w * w);
        float4 ov = make_float4(av.x * w, av.y * w, av.z * w, av.w * w);
        ((float4*)(sums + (size_t)b * C_ * D_))[c * 16 + d4] = oq;
        ((float4*)(sums + ((size_t)B_ + b) * C_ * D_))[c * 16 + d4] = ok;
        ((float4*)(sums + ((size_t)2 * B_ + b) * C_ * D_))[c * 16 + d4] = ov;
    }
}

// ---------------------------------------------------------------- attention + scatter
// Unchanged from round 6 (best: 164.7 us). 544 blocks, 2/CU, XCD-local per b.
__global__ __launch_bounds__(256, 2) void k_attn_sc(const float* __restrict__ sums,
                                                    const float* __restrict__ counts,
                                                    const int* __restrict__ offsets,
                                                    const int* __restrict__ sidx,
                                                    float* __restrict__ out,
                                                    float* __restrict__ aout) {
    __shared__ float4 kc4[C_ * 17];       // K centers, 16 data float4 + 1 pad
    __shared__ float4 vc4[C_ * 17];       // V centers
    __shared__ float cnt_s[C_];
    __shared__ float arow[4][2][132];     // per-wave A rows (2-row tiles)

    int bid = blockIdx.x;
    int b = bid & 31;          // XCD-locality: blocks of batch b are == b (mod 32)
    int qg = bid >> 5;         // 0..16
    int q0 = qg * QROWS_;
    int qcnt = min(QROWS_, C_ - q0);
    int tid = threadIdx.x;
    int bc = b & 3;

    for (int i = tid; i < C_; i += 256)
        cnt_s[i] = counts[bc * C_ + i];

    const float4* qsum4 = (const float4*)(sums + (size_t)b * C_ * D_);
    const float4* ksum4 = (const float4*)(sums + ((size_t)B_ + b) * C_ * D_);
    const float4* vsum4 = (const float4*)(sums + ((size_t)2 * B_ + b) * C_ * D_);

    for (int i = tid; i < C_ * 16; i += 256) {
        int c = i >> 4, d4 = i & 15;
        kc4[c * 17 + d4] = ksum4[i];
        vc4[c * 17 + d4] = vsum4[i];
    }
    __syncthreads();

    const int* si = sidx + bc * N_;
    float4* ob = (float4*)(out + (size_t)b * N_ * D_);

    int wave = __builtin_amdgcn_readfirstlane(tid >> 6);
    int lane = tid & 63;

    for (int tt = wave; tt * 2 < qcnt; tt += 4) {
        int t2 = tt * 2;
        const float4* qp0 = qsum4 + (size_t)(q0 + min(t2 + 0, qcnt - 1)) * 16;
        const float4* qp1 = qsum4 + (size_t)(q0 + min(t2 + 1, qcnt - 1)) * 16;
        float s0[2] = {0, 0}, s1[2] = {0, 0}, s2[2] = {0, 0};
#pragma unroll 4
        for (int d4 = 0; d4 < 16; d4++) {
            float4 kv0 = kc4[lane * 17 + d4];
            float4 kv1 = kc4[(lane + 64) * 17 + d4];
            float4 kv2 = kc4[128 * 17 + d4];
            float4 qv0 = qp0[d4], qv1 = qp1[d4];
            s0[0] += qv0.x * kv0.x + qv0.y * kv0.y + qv0.z * kv0.z + qv0.w * kv0.w;
            s1[0] += qv0.x * kv1.x + qv0.y * kv1.y + qv0.z * kv1.z + qv0.w * kv1.w;
            s2[0] += qv0.x * kv2.x + qv0.y * kv2.y + qv0.z * kv2.z + qv0.w * kv2.w;
            s0[1] += qv1.x * kv0.x + qv1.y * kv0.y + qv1.z * kv0.z + qv1.w * kv0.w;
            s1[1] += qv1.x * kv1.x + qv1.y * kv1.y + qv1.z * kv1.z + qv1.w * kv1.w;
            s2[1] += qv1.x * kv2.x + qv1.y * kv2.y + qv1.z * kv2.z + qv1.w * kv2.w;
        }
#pragma unroll
        for (int r = 0; r < 2; r++) {
            if (t2 + r >= qcnt) break;
            int qrow = q0 + t2 + r;
            float m = fmaxf(s0[r], s1[r]);
            if (lane == 0) m = fmaxf(m, s2[r]);
            for (int off = 32; off > 0; off >>= 1)
                m = fmaxf(m, __shfl_xor(m, off, 64));
            float e0 = __expf(s0[r] - m) * cnt_s[lane];
            float e1 = __expf(s1[r] - m) * cnt_s[lane + 64];
            float e2 = (lane == 0) ? __expf(s2[r] - m) * cnt_s[128] : 0.f;
            float sum = e0 + e1 + e2;
            for (int off = 32; off > 0; off >>= 1)
                sum += __shfl_xor(sum, off, 64);
            float inv = 1.f / sum;
            float a0 = e0 * inv, a1 = e1 * inv;
            arow[wave][r][lane] = a0;
            arow[wave][r][64 + lane] = a1;
            if (lane == 0) {
                arow[wave][r][128] = e2 * inv;
                aout[b * C_ + qrow] = a0;   // A_full[:, :, 0]
            }
        }
        __builtin_amdgcn_s_waitcnt(0);       // arow writes visible in-wave
        __builtin_amdgcn_sched_barrier(0);   // don't let ds_reads hoist above
        int rr = lane >> 5;
        int half = (lane >> 4) & 1;
        int d4 = lane & 15;
        const float4* ar4 = (const float4*)arow[wave][rr];
        float4 o = make_float4(0.f, 0.f, 0.f, 0.f);
        int k4base = half * 16;
        for (int k4 = k4base; k4 < k4base + 16; k4++) {
            float4 a4 = ar4[k4];
            float4 v0 = vc4[(k4 * 4 + 0) * 17 + d4];
            float4 v1 = vc4[(k4 * 4 + 1) * 17 + d4];
            float4 v2 = vc4[(k4 * 4 + 2) * 17 + d4];
            float4 v3 = vc4[(k4 * 4 + 3) * 17 + d4];
            o.x += a4.x * v0.x + a4.y * v1.x + a4.z * v2.x + a4.w * v3.x;
            o.y += a4.x * v0.y + a4.y * v1.y + a4.z * v2.y + a4.w * v3.y;
            o.z += a4.x * v0.z + a4.y * v1.z + a4.z * v2.z + a4.w * v3.z;
            o.w += a4.x * v0.w + a4.y * v1.w + a4.z * v2.w + a4.w * v3.w;
        }
        o.x += __shfl_xor(o.x, 16, 64);
        o.y += __shfl_xor(o.y, 16, 64);
        o.z += __shfl_xor(o.z, 16, 64);
        o.w += __shfl_xor(o.w, 16, 64);
        {   // k=128 tail (identical in both halves; added AFTER the combine)
            float a128 = arow[wave][rr][128];
            float4 vv = vc4[128 * 17 + d4];
            o.x += a128 * vv.x; o.y += a128 * vv.y;
            o.z += a128 * vv.z; o.w += a128 * vv.w;
        }
        if (t2 + rr < qcnt) {
            int qrow = q0 + t2 + rr;
            int s = offsets[bc * (C_ + 1) + qrow];
            int e = offsets[bc * (C_ + 1) + qrow + 1];
            for (int mm = s + half; mm < e; mm += 2) {
                int n = si[mm];              // broadcast load (same addr, 16 lanes)
                ob[n * 16 + d4] = o;         // 16 lanes -> contiguous 256B row
            }
        }
    }
}

// ---------------------------------------------------------------- launch
extern "C" void kernel_launch(void* const* d_in, const int* in_sizes, int n_in,
                              void* d_out, int out_size, void* d_ws, size_t ws_size,
                              hipStream_t stream) {
    const float* q = (const float*)d_in[0];
    const float* k = (const float*)d_in[1];
    const float* v = (const float*)d_in[2];
    const int* cl = (const int*)d_in[3];
    float* out = (float*)d_out;
    float* aout = out + (size_t)B_ * N_ * D_;   // A_full[:, :, 0] tail

    float* ws = (float*)d_ws;
    float* counts = ws;                                   // [4][C_] (pad to 1024)
    float* sums = ws + 1024;                              // [3][B_][C_][D_] pre-scaled centers
    int* offsets = (int*)(sums + (size_t)3 * B_ * C_ * D_); // [4][C_+1]
    int* sidx = offsets + 4 * (C_ + 1);                   // [4][N_]

    k_sort<<<BC_ + PFB_, 1024, 0, stream>>>(q, k, v, cl, counts, offsets, sidx);
    k_segsum4<<<B_ * CG_, 256, 0, stream>>>(q, k, v, offsets, sidx, sums);
    k_attn_sc<<<17 * B_, 256, 0, stream>>>(sums, counts, offsets, sidx, out, aout);
}